// Round 2
// baseline (1000.180 us; speedup 1.0000x reference)
//
#include <hip/hip_runtime.h>
#include <hip/hip_bf16.h>

#define N_NODES 2048
#define N_EDGES 65536
#define D_IN    64
#define D_OUT   64
#define GAT_EPS 1e-6f

typedef unsigned short u16;
typedef unsigned int   u32;
typedef __attribute__((ext_vector_type(8))) short frag8;   // 8 bf16 = 4 VGPRs
typedef __attribute__((ext_vector_type(4))) float f32x4;

__device__ __forceinline__ u16 f2bf(float f) {
    union { u32 u; float f; } x; x.f = f;
    u32 lsb = (x.u >> 16) & 1u;
    x.u += 0x7fffu + lsb;           // round-to-nearest-even
    return (u16)(x.u >> 16);
}

// ---------------- zero two f32 regions ----------------
__global__ void k_zero2(float* __restrict__ a, int na, float* __restrict__ b, int nb) {
    int i = blockIdx.x * 256 + threadIdx.x;
    if (i < na) a[i] = 0.0f;
    else if (i - na < nb) b[i - na] = 0.0f;
}

// ---------------- index extraction from one-hot [N,E] f32 ----------------
// Each thread reads 16B = 4 f32 along E (coalesced). Exactly one nonzero per
// column, so each idx[e] has exactly one writer.
__global__ void k_extract2(const uint4* __restrict__ src, const uint4* __restrict__ tgt,
                           int* __restrict__ sidx, int* __restrict__ tidx) {
    u32 b = blockIdx.x;
    const uint4* m; int* idx;
    if (b < 131072u) { m = src; idx = sidx; }
    else             { m = tgt; idx = tidx; b -= 131072u; }
    u32 t = b * 256u + threadIdx.x;          // [0, N*E/4)
    uint4 v = m[t];
    if (v.x | v.y | v.z | v.w) {
        u32 elem = t * 4u;                   // flat index n*65536 + e
        int n = (int)(elem >> 16);           // E = 65536
        int e = (int)(elem & 65535u);
        if (v.x) idx[e]     = n;
        if (v.y) idx[e + 1] = n;
        if (v.z) idx[e + 2] = n;
        if (v.w) idx[e + 3] = n;
    }
}

// ---------------- per-edge attention score a[e] = h . W_w + b_w -----------
__global__ void k_edge_score(const float* __restrict__ x,
                             const int* __restrict__ sidx, const int* __restrict__ tidx,
                             const float* __restrict__ Ww, const float* __restrict__ bw,
                             float* __restrict__ a, float* __restrict__ mean_acc) {
    __shared__ float ww[2 * D_IN];
    int tid = threadIdx.x;
    if (tid < 2 * D_IN) ww[tid] = Ww[tid];
    __syncthreads();
    int e = blockIdx.x * 256 + tid;
    int s = sidx[e] & (N_NODES - 1);         // defensive clamp: no faults ever
    int t = tidx[e] & (N_NODES - 1);
    const float4* xs = (const float4*)(x + s * D_IN);
    const float4* xt = (const float4*)(x + t * D_IN);
    float sum = bw[0];
    #pragma unroll
    for (int i = 0; i < 16; ++i) {
        float4 v = xs[i];
        sum += v.x * ww[i * 4] + v.y * ww[i * 4 + 1]
             + v.z * ww[i * 4 + 2] + v.w * ww[i * 4 + 3];
    }
    #pragma unroll
    for (int i = 0; i < 16; ++i) {
        float4 v = xt[i];
        sum += v.x * ww[D_IN + i * 4] + v.y * ww[D_IN + i * 4 + 1]
             + v.z * ww[D_IN + i * 4 + 2] + v.w * ww[D_IN + i * 4 + 3];
    }
    a[e] = sum;
    float r = sum;
    #pragma unroll
    for (int off = 32; off; off >>= 1) r += __shfl_down(r, off);
    if ((tid & 63) == 0) atomicAdd(mean_acc, r);
}

// ---------------- a_exp + per-target denominator ----------------
__global__ void k_softmax_prep(const float* __restrict__ a, const int* __restrict__ tidx,
                               const float* __restrict__ mean_acc,
                               float* __restrict__ a_exp, float* __restrict__ a_sum) {
    int e = blockIdx.x * 256 + threadIdx.x;
    float mean = mean_acc[0] * (1.0f / (float)N_EDGES);
    float ae = expf(a[e] - mean);
    a_exp[e] = ae;
    atomicAdd(&a_sum[tidx[e] & (N_NODES - 1)], ae);
}

// ---------------- MFMA GEMM y=relu(h@W_f+b_f), fused attention scatter ----
// Wave handles 16 edges x 64 dims (4 dim-tiles of 16x16, K=128 via 4 chunks).
// A frags gathered from f32 x rows (converted to bf16 on the fly).
__global__ void __launch_bounds__(256) k_gemm_scatter(
        const float* __restrict__ x,
        const int* __restrict__ sidx, const int* __restrict__ tidx,
        const float* __restrict__ Wf, const float* __restrict__ bf,
        const float* __restrict__ a_exp, const float* __restrict__ a_sum,
        float* __restrict__ out) {
    __shared__ u16 wt[D_OUT * 2 * D_IN];   // wt[d][k], k contiguous (16KB)
    int tid = threadIdx.x;
    for (int i = tid; i < 2 * D_IN * D_OUT; i += 256) {
        int k = i >> 6, d = i & 63;        // Wf is [128][64] row-major f32
        wt[d * 128 + k] = f2bf(Wf[i]);
    }
    __syncthreads();

    int wave = tid >> 6, lane = tid & 63;
    int q = lane >> 4, r = lane & 15;
    int e0 = blockIdx.x * 64 + wave * 16;

    // A operand: lane holds A[m = lane&15][k = q*8 + j]; h = [x[s], x[t]]
    int s_r = sidx[e0 + r] & (N_NODES - 1);
    int t_r = tidx[e0 + r] & (N_NODES - 1);
    const float* xs = x + s_r * D_IN;
    const float* xt = x + t_r * D_IN;
    frag8 afr[4];
    #pragma unroll
    for (int c = 0; c < 4; ++c) {
        const float* base = (c < 2 ? xs : xt) + (c & 1) * 32 + q * 8;
        float4 lo = *(const float4*)(base);
        float4 hi = *(const float4*)(base + 4);
        frag8 f;
        f[0] = (short)f2bf(lo.x); f[1] = (short)f2bf(lo.y);
        f[2] = (short)f2bf(lo.z); f[3] = (short)f2bf(lo.w);
        f[4] = (short)f2bf(hi.x); f[5] = (short)f2bf(hi.y);
        f[6] = (short)f2bf(hi.z); f[7] = (short)f2bf(hi.w);
        afr[c] = f;
    }

    f32x4 acc[4] = { {0,0,0,0}, {0,0,0,0}, {0,0,0,0}, {0,0,0,0} };
    #pragma unroll
    for (int c = 0; c < 4; ++c) {
        #pragma unroll
        for (int dt = 0; dt < 4; ++dt) {
            // B operand: lane holds B[k = q*8+j][n = lane&15] = Wf[k][dt*16+r]
            frag8 bfr = *(const frag8*)(&wt[(dt * 16 + r) * 128 + c * 32 + q * 8]);
            acc[dt] = __builtin_amdgcn_mfma_f32_16x16x32_bf16(afr[c], bfr, acc[dt], 0, 0, 0);
        }
    }

    // C/D layout: col = lane&15 (dim), row = q*4 + reg (edge)
    float wgt[4]; int tg[4];
    #pragma unroll
    for (int reg = 0; reg < 4; ++reg) {
        int e = e0 + q * 4 + reg;
        int tt = tidx[e] & (N_NODES - 1);
        tg[reg] = tt;
        wgt[reg] = a_exp[e] / (a_sum[tt] + GAT_EPS);
    }
    #pragma unroll
    for (int dt = 0; dt < 4; ++dt) {
        int d = dt * 16 + r;
        float bias = bf[d];
        #pragma unroll
        for (int reg = 0; reg < 4; ++reg) {
            float y = acc[dt][reg] + bias;
            y = y > 0.0f ? y : 0.0f;
            atomicAdd(&out[tg[reg] * D_OUT + d], y * wgt[reg]);
        }
    }
}

extern "C" void kernel_launch(void* const* d_in, const int* in_sizes, int n_in,
                              void* d_out, int out_size, void* d_ws, size_t ws_size,
                              hipStream_t stream) {
    const float* x   = (const float*)d_in[0];
    const float* src = (const float*)d_in[1];
    const float* tgt = (const float*)d_in[2];
    const float* Wf  = (const float*)d_in[3];
    const float* bf  = (const float*)d_in[4];
    const float* Ww  = (const float*)d_in[5];
    const float* bw  = (const float*)d_in[6];
    float* out = (float*)d_out;

    char* ws = (char*)d_ws;
    // ws layout: [mean_acc 16B | a_sum 2048 f32 | sidx | tidx | a | a_exp]
    float* mean_acc = (float*)(ws);
    float* a_sum    = (float*)(ws + 16);
    int*   sidx     = (int*)  (ws + 16 + 2048 * 4);                  // off 8208
    int*   tidx     = (int*)  (ws + 8208 + 262144);
    float* a        = (float*)(ws + 8208 + 2 * 262144);
    float* a_exp    = (float*)(ws + 8208 + 3 * 262144);

    const int n_zero_ws  = 4 + 2048;                 // mean_acc + a_sum
    const int n_zero_out = N_NODES * D_OUT;          // 131072
    k_zero2<<<(n_zero_ws + n_zero_out + 255) / 256, 256, 0, stream>>>(
        (float*)ws, n_zero_ws, out, n_zero_out);
    k_extract2<<<262144, 256, 0, stream>>>((const uint4*)src, (const uint4*)tgt, sidx, tidx);
    k_edge_score<<<N_EDGES / 256, 256, 0, stream>>>(x, sidx, tidx, Ww, bw, a, mean_acc);
    k_softmax_prep<<<N_EDGES / 256, 256, 0, stream>>>(a, tidx, mean_acc, a_exp, a_sum);
    k_gemm_scatter<<<N_EDGES / 64, 256, 0, stream>>>(x, sidx, tidx, Wf, bf, a_exp, a_sum, out);
}

// Round 3
// 996.966 us; speedup vs baseline: 1.0032x; 1.0032x over previous
//
#include <hip/hip_runtime.h>
#include <hip/hip_bf16.h>

#define N_NODES 2048
#define N_EDGES 65536
#define D_IN    64
#define D_OUT   64
#define GAT_EPS 1e-6f

typedef unsigned short u16;
typedef unsigned int   u32;
typedef __attribute__((ext_vector_type(8))) short frag8;   // 8 bf16 = 4 VGPRs
typedef __attribute__((ext_vector_type(4))) float f32x4;

__device__ __forceinline__ u16 f2bf(float f) {
    union { u32 u; float f; } x; x.f = f;
    u32 lsb = (x.u >> 16) & 1u;
    x.u += 0x7fffu + lsb;           // round-to-nearest-even
    return (u16)(x.u >> 16);
}

// ---------------- index extraction from one-hot [N,E] f32 ----------------
// 4096 blocks: [0,2048) scan src, [2048,4096) scan tgt. Each thread does 64
// coalesced uint4 (16B) loads with grid-wide stride -> 64 outstanding-load
// slots per wave instead of 1, and 64x fewer workgroups than round 2.
// Blocks < 520 additionally zero a_sum + out_acc (133120 f32) before the
// dependent kernels run (stream order guarantees completion).
__global__ void k_extract(const uint4* __restrict__ src, const uint4* __restrict__ tgt,
                          int* __restrict__ sidx, int* __restrict__ tidx,
                          float* __restrict__ zero_base) {
    u32 b = blockIdx.x, tid = threadIdx.x;
    if (b < 520u) {
        u32 zi = b * 256u + tid;
        if (zi < 133120u) zero_base[zi] = 0.0f;
    }
    const uint4* m; int* idx;
    if (b < 2048u) { m = src; idx = sidx; }
    else           { m = tgt; idx = tidx; b -= 2048u; }
    u32 t0 = b * 256u + tid;
    const u32 S = 524288u;                    // grid stride in uint4
    #pragma unroll 4
    for (u32 it = 0; it < 64u; ++it) {
        u32 t = t0 + it * S;                  // < N*E/4 = 33554432
        uint4 v = m[t];
        if (v.x | v.y | v.z | v.w) {
            u32 elem = t * 4u;                // flat n*65536 + e
            int n = (int)(elem >> 16);        // E = 65536
            int e = (int)(elem & 65535u);
            if (v.x) idx[e]     = n;
            if (v.y) idx[e + 1] = n;
            if (v.z) idx[e + 2] = n;
            if (v.w) idx[e + 3] = n;
        }
    }
}

// ---------------- fused: score + exp + a_sum, MFMA GEMM, scatter ----------
// Wave handles 16 edges x 64 dims. A-fragments gathered from f32 x rows
// (converted to bf16 in-register); the SAME loaded values feed the attention
// score dot with Ww (softmax shift dropped: it cancels in the ratio up to a
// ~1e-8 relative eps perturbation). Scatter accumulates y*exp(a) unnormalized;
// k_norm divides by (a_sum+eps) afterwards.
__global__ void __launch_bounds__(256) k_fused(
        const float* __restrict__ x,
        const int* __restrict__ sidx, const int* __restrict__ tidx,
        const float* __restrict__ Wf, const float* __restrict__ bf,
        const float* __restrict__ Ww, const float* __restrict__ bw,
        float* __restrict__ a_sum, float* __restrict__ out_acc) {
    __shared__ u16 wt[D_OUT * 2 * D_IN];      // wt[d][k], k contiguous (16KB)
    __shared__ float ww[2 * D_IN];            // attention weights f32
    int tid = threadIdx.x;
    if (tid < 2 * D_IN) ww[tid] = Ww[tid];
    for (int i = tid; i < 2 * D_IN * D_OUT; i += 256) {
        int k = i >> 6, d = i & 63;           // Wf is [128][64] row-major f32
        wt[d * 128 + k] = f2bf(Wf[i]);
    }
    __syncthreads();

    int wave = tid >> 6, lane = tid & 63;
    int q = lane >> 4, r = lane & 15;
    int e0 = blockIdx.x * 64 + wave * 16;

    int s_r = sidx[e0 + r] & (N_NODES - 1);   // defensive clamp
    int t_r = tidx[e0 + r] & (N_NODES - 1);
    const float* xs = x + s_r * D_IN;
    const float* xt = x + t_r * D_IN;

    // A operand: lane holds A[m = lane&15][k = q*8 + j]; h = [x[s], x[t]]
    frag8 afr[4];
    float part = 0.0f;
    #pragma unroll
    for (int c = 0; c < 4; ++c) {
        const float* base = (c < 2 ? xs : xt) + (c & 1) * 32 + q * 8;
        int kb = (c >> 1) * 64 + (c & 1) * 32 + q * 8;
        float4 lo = *(const float4*)(base);
        float4 hi = *(const float4*)(base + 4);
        part += lo.x * ww[kb]     + lo.y * ww[kb + 1]
              + lo.z * ww[kb + 2] + lo.w * ww[kb + 3]
              + hi.x * ww[kb + 4] + hi.y * ww[kb + 5]
              + hi.z * ww[kb + 6] + hi.w * ww[kb + 7];
        frag8 f;
        f[0] = (short)f2bf(lo.x); f[1] = (short)f2bf(lo.y);
        f[2] = (short)f2bf(lo.z); f[3] = (short)f2bf(lo.w);
        f[4] = (short)f2bf(hi.x); f[5] = (short)f2bf(hi.y);
        f[6] = (short)f2bf(hi.z); f[7] = (short)f2bf(hi.w);
        afr[c] = f;
    }
    // each lane covers k = kb..kb+7 over its 4 chunks; reduce over the 4
    // lanes sharing r (q = 0..3): xor-16 + xor-32 leaves the full score
    // for edge e0+r in ALL of those lanes.
    part += __shfl_xor(part, 16);
    part += __shfl_xor(part, 32);
    float ae = expf(part + bw[0]);            // unshifted exp (shift cancels)
    if (lane < 16) atomicAdd(&a_sum[t_r], ae);

    f32x4 acc[4] = { {0,0,0,0}, {0,0,0,0}, {0,0,0,0}, {0,0,0,0} };
    #pragma unroll
    for (int c = 0; c < 4; ++c) {
        #pragma unroll
        for (int dt = 0; dt < 4; ++dt) {
            // B operand: lane holds B[k = q*8+j][n = lane&15] = Wf[k][dt*16+r]
            frag8 bfr = *(const frag8*)(&wt[(dt * 16 + r) * 128 + c * 32 + q * 8]);
            acc[dt] = __builtin_amdgcn_mfma_f32_16x16x32_bf16(afr[c], bfr, acc[dt], 0, 0, 0);
        }
    }

    // C/D layout: col = lane&15 (dim), row = q*4 + reg (edge)
    #pragma unroll
    for (int reg = 0; reg < 4; ++reg) {
        float w  = __shfl(ae,  q * 4 + reg);  // lane (q*4+reg) holds that edge
        int   tg = __shfl(t_r, q * 4 + reg);
        #pragma unroll
        for (int dt = 0; dt < 4; ++dt) {
            int d = dt * 16 + r;
            float y = acc[dt][reg] + bf[d];
            y = y > 0.0f ? y : 0.0f;
            atomicAdd(&out_acc[tg * D_OUT + d], y * w);
        }
    }
}

// ---------------- normalize: out = out_acc / (a_sum + eps) ----------------
__global__ void k_norm(const float* __restrict__ out_acc, const float* __restrict__ a_sum,
                       float* __restrict__ out) {
    int i = blockIdx.x * 256 + threadIdx.x;   // 131072
    out[i] = out_acc[i] / (a_sum[i >> 6] + GAT_EPS);
}

extern "C" void kernel_launch(void* const* d_in, const int* in_sizes, int n_in,
                              void* d_out, int out_size, void* d_ws, size_t ws_size,
                              hipStream_t stream) {
    const float* x   = (const float*)d_in[0];
    const float* src = (const float*)d_in[1];
    const float* tgt = (const float*)d_in[2];
    const float* Wf  = (const float*)d_in[3];
    const float* bf  = (const float*)d_in[4];
    const float* Ww  = (const float*)d_in[5];
    const float* bw  = (const float*)d_in[6];
    float* out = (float*)d_out;

    char* ws = (char*)d_ws;
    // ws layout: [a_sum 2048 f32 | out_acc 131072 f32 | sidx | tidx]
    float* a_sum   = (float*)(ws);
    float* out_acc = (float*)(ws + 8192);
    int*   sidx    = (int*)  (ws + 8192 + 524288);        // 532480
    int*   tidx    = (int*)  (ws + 532480 + 262144);      // 794624

    k_extract<<<4096, 256, 0, stream>>>((const uint4*)src, (const uint4*)tgt,
                                        sidx, tidx, (float*)ws);
    k_fused<<<N_EDGES / 64, 256, 0, stream>>>(x, sidx, tidx, Wf, bf, Ww, bw,
                                              a_sum, out_acc);
    k_norm<<<(N_NODES * D_OUT) / 256, 256, 0, stream>>>(out_acc, a_sum, out);
}